// Round 7
// baseline (55.658 us; speedup 1.0000x reference)
//
#include <hip/hip_runtime.h>

#define FLOOR_EPS 1e-6f

typedef float floatx4 __attribute__((ext_vector_type(4)));  // native vec for nt-store

// Problem shape (from reference): B=32, C=1, F=128, T=8000
constexpr int Bq = 32, Cq = 1, Fq = 128, Tq = 8000;
constexpr int ROWS  = Bq * Cq * Fq;             // 4096 independent rows
constexpr int LPR   = 8;                        // elems per lane per round
constexpr int RNDE  = 64 * LPR;                 // 512 elems per round per wave
constexpr int SPLIT = 4;                        // segments per row (temporal split)
constexpr int MAIN  = Tq / SPLIT;               // 2000 elems per segment
constexpr int NRM   = (MAIN + RNDE - 1) / RNDE; // 4 main rounds (last partial)
constexpr int LACT  = (MAIN - (NRM - 1) * RNDE) / LPR; // 58 active lanes, last round
constexpr int WPB   = 4;                        // waves per block
constexpr int NSEG  = ROWS * SPLIT;             // 16384 segments
constexpr int NWAVE = NSEG / 2;                 // 8192 waves, 2 segments each
constexpr unsigned TOTE = (unsigned)ROWS * Tq;  // total elements (fits 32-bit)

__global__ __launch_bounds__(256)
void _PCEN_75033078661345_kernel(const float* __restrict__ x,
                                 const float* __restrict__ alpha,
                                 const float* __restrict__ delta,
                                 const float* __restrict__ root,
                                 const float* __restrict__ smooth,
                                 float* __restrict__ out,   // ROWS*T
                                 float* __restrict__ hid)   // ROWS
{
    const int lane = threadIdx.x & 63;
    const int wid  = threadIdx.x >> 6;
    const int gw   = blockIdx.x * WPB + wid;   // wave id, 0..NWAVE-1
    // Two segments per wave, same quarter h -> identical wave-uniform control flow
    const int h  = gw & 3;
    const int rA = gw >> 2;                    // rows 0..2047
    const int rB = rA + (NWAVE >> 2);          // rows 2048..4095

    // Cq==1 -> channel params are uniform (c==0)
    const float w   = fminf(fmaxf(smooth[0], 0.f), 1.f);
    const float om  = 1.f - w;
    const float aa  = fminf(alpha[0], 1.f);
    const float dd  = delta[0];
    const float oor = 1.f / fmaxf(root[0], 1.f);
    const bool  us  = (oor == 0.5f);
    const float droot = us ? __builtin_amdgcn_sqrtf(dd)
                           : __builtin_amdgcn_exp2f(oor * __builtin_amdgcn_logf(dd));

    // omp[k] = om^(8 * 2^k) by squaring; om8i = om^(8*lane); omR = om^512
    float om2 = om * om, om4 = om2 * om2;
    float omp[6];
    omp[0] = om4 * om4;
    #pragma unroll
    for (int k = 1; k < 6; ++k) omp[k] = omp[k - 1] * omp[k - 1];
    float om8i = 1.f;
    #pragma unroll
    for (int k = 0; k < 6; ++k) om8i = ((lane >> k) & 1) ? om8i * omp[k] : om8i;
    const float omR = omp[5] * omp[5];

    // Warmup rounds for h>0: window W=Rw*512 with om^W <= ~2^-30 (runtime-adaptive).
    int Rw = 0;
    if (h) {
        const float nl2 = fmaxf(-__builtin_amdgcn_logf(om), 1e-9f); // -log2(om)
        float need = 30.f / (512.f * nl2);
        int ri = (int)ceilf(need);
        const int cap = (h * MAIN) / RNDE;     // keep w0 >= 0
        Rw = ri < 1 ? 1 : ri;
        Rw = Rw > 3 ? 3 : Rw;
        Rw = Rw > cap ? cap : Rw;
    }
    const int w0 = h * MAIN - Rw * RNDE;       // first round's base element in row
    const int nr = NRM + Rw;                   // total rounds per segment

    const unsigned baseA = (unsigned)rA * (unsigned)Tq;
    const unsigned baseB = (unsigned)rB * (unsigned)Tq;

    float carryA = x[baseA + (unsigned)w0];    // EMA state entering element w0
    float carryB = x[baseB + (unsigned)w0];
    float accA = 0.f, accB = 0.f;

    auto LOADR = [&](unsigned base, int sidx, float4& d0, float4& d1) {
        unsigned u = base + (unsigned)(w0 + sidx * RNDE + lane * LPR);
        u = u > (TOTE - LPR) ? (TOTE - LPR) : u;   // clamp only matters at buffer end
        const float4* p = (const float4*)(x + u);
        d0 = p[0]; d1 = p[1];
    };

    auto ROUND = [&](unsigned base, int sidx, float4 c0, float4 c1,
                     float& carry, float& accv) {
        const float xv[LPR] = {c0.x, c0.y, c0.z, c0.w, c1.x, c1.y, c1.z, c1.w};
        // local affine offset over 8 elems (coefficient om^8 uniform)
        float b = 0.f;
        #pragma unroll
        for (int j = 0; j < LPR; ++j) b = w * xv[j] + om * b;
        // Kogge-Stone scan with constant per-level coefficient: 6 shuffles
        #pragma unroll
        for (int k = 0; k < 6; ++k) {
            const float pb = __shfl_up(b, 1 << k);
            const float nb = fmaf(omp[k], pb, b);
            b = (lane >= (1 << k)) ? nb : b;
        }
        const float pb1  = __shfl_up(b, 1);
        const float bex  = (lane == 0) ? 0.f : pb1;
        float acc        = fmaf(om8i, carry, bex);   // state entering this lane
        const float btot = __shfl(b, 63);
        carry = fmaf(omR, carry, btot);              // state after this round
        if (sidx >= Rw) {                            // main region: pointwise + store
            float ov[LPR];
            #pragma unroll
            for (int j = 0; j < LPR; ++j) {
                acc = w * xv[j] + om * acc;          // exact sequential EMA
                const float dp = __builtin_amdgcn_exp2f(-aa * __builtin_amdgcn_logf(FLOOR_EPS + acc));
                const float tt = fmaf(xv[j], dp, dd);
                ov[j] = us ? (__builtin_amdgcn_sqrtf(tt) - droot)
                           : (__builtin_amdgcn_exp2f(oor * __builtin_amdgcn_logf(tt)) - droot);
            }
            const bool lastr = (sidx == nr - 1);
            if (!lastr || lane < LACT) {
                floatx4* q = (floatx4*)(out + base + (unsigned)(w0 + sidx * RNDE + lane * LPR));
                floatx4 o0 = {ov[0], ov[1], ov[2], ov[3]};
                floatx4 o1 = {ov[4], ov[5], ov[6], ov[7]};
                __builtin_nontemporal_store(o0, q);
                __builtin_nontemporal_store(o1, q + 1);
            }
            accv = acc;
        }
    };

    // ---- 2-deep prefetch per segment, rounds of the two segments interleaved
    float4 XA0, XA1, XB0, XB1;     // segment A buffers
    float4 YA0, YA1, YB0, YB1;     // segment B buffers
    LOADR(baseA, 0, XA0, XA1);  LOADR(baseB, 0, YA0, YA1);
    LOADR(baseA, 1, XB0, XB1);  LOADR(baseB, 1, YB0, YB1);
    int s = 0;
    for (; s + 1 < nr; s += 2) {
        float4 a0 = XA0, a1 = XA1, b0 = YA0, b1 = YA1;
        if (s + 2 < nr) { LOADR(baseA, s + 2, XA0, XA1); LOADR(baseB, s + 2, YA0, YA1); }
        ROUND(baseA, s, a0, a1, carryA, accA);   // two independent carry chains:
        ROUND(baseB, s, b0, b1, carryB, accB);   // B's scan issues under A's DS waits
        a0 = XB0; a1 = XB1; b0 = YB0; b1 = YB1;
        if (s + 3 < nr) { LOADR(baseA, s + 3, XB0, XB1); LOADR(baseB, s + 3, YB0, YB1); }
        ROUND(baseA, s + 1, a0, a1, carryA, accA);
        ROUND(baseB, s + 1, b0, b1, carryB, accB);
    }
    if (s < nr) {
        ROUND(baseA, s, XA0, XA1, carryA, accA);
        ROUND(baseB, s, YA0, YA1, carryB, accB);
    }

    // hidden state = final EMA of each row, owned by the last-quarter waves
    const float hA = __shfl(accA, LACT - 1);
    const float hB = __shfl(accB, LACT - 1);
    if (h == SPLIT - 1 && lane == 0) { hid[rA] = hA; hid[rB] = hB; }
}

extern "C" void kernel_launch(void* const* d_in, const int* in_sizes, int n_in,
                              void* d_out, int out_size, void* d_ws, size_t ws_size,
                              hipStream_t stream) {
    const float* x      = (const float*)d_in[0];
    const float* alpha  = (const float*)d_in[1];
    const float* delta  = (const float*)d_in[2];
    const float* root   = (const float*)d_in[3];
    const float* smooth = (const float*)d_in[4];
    float* out = (float*)d_out;
    float* hid = out + (size_t)ROWS * Tq;

    _PCEN_75033078661345_kernel<<<NWAVE / WPB, 256, 0, stream>>>(
        x, alpha, delta, root, smooth, out, hid);
}